// Round 5
// baseline (282.800 us; speedup 1.0000x reference)
//
#include <hip/hip_runtime.h>

#define N_NODES  50000
#define N_EDGES  800000
#define N_GRAPHS 2000
#define N_PAIRS  4096
#define IN_CH    64
#define EMB      128
#define HID      256
#define PPB      16

// ---------------- pre pass: in-degree + per-edge rank + graph counts + weight transposes ----------------
__global__ void k_pre(const int* __restrict__ col, const int* __restrict__ batch,
                      const float* __restrict__ w1, const float* __restrict__ w2,
                      int* __restrict__ deg, int* __restrict__ pos_e, int* __restrict__ cnt,
                      float* __restrict__ wt1, float* __restrict__ wt2) {
    int e = blockIdx.x * 256 + threadIdx.x;
    if (e < N_EDGES) {
        int c = col[e];
        pos_e[e] = atomicAdd(&deg[c], 1);
    }
    if (e < N_NODES) atomicAdd(&cnt[batch[e]], 1);
    if (e < EMB * IN_CH) {
        int j = e / IN_CH, k = e % IN_CH;
        wt1[k * EMB + j] = w1[e];
    } else if (e < EMB * IN_CH + EMB * EMB) {
        int t = e - EMB * IN_CH;
        int j = t / EMB, k = t % EMB;
        wt2[k * EMB + j] = w2[t];
    }
}

// ---------------- multi-block exclusive scan ----------------
__device__ inline int wave_incl_scan(int x, int lane) {
    #pragma unroll
    for (int off = 1; off < 64; off <<= 1) {
        int y = __shfl_up(x, off, 64);
        if (lane >= off) x += y;
    }
    return x;
}

__global__ void k_scan1(const int* __restrict__ in, int* __restrict__ part, int n) {
    __shared__ int ws[4];
    int i = blockIdx.x * 256 + threadIdx.x;
    int lane = threadIdx.x & 63, wid = threadIdx.x >> 6;
    int v = (i < n) ? in[i] : 0;
    int x = wave_incl_scan(v, lane);
    if (lane == 63) ws[wid] = x;
    __syncthreads();
    if (threadIdx.x == 0) part[blockIdx.x] = ws[0] + ws[1] + ws[2] + ws[3];
}

__global__ void k_scan2(int* __restrict__ part, int nb) {   // single block, nb <= 256
    __shared__ int ws[4];
    int t = threadIdx.x, lane = t & 63, wid = t >> 6;
    int v = (t < nb) ? part[t] : 0;
    int x = wave_incl_scan(v, lane);
    if (lane == 63) ws[wid] = x;
    __syncthreads();
    int add = 0;
    for (int w = 0; w < wid; ++w) add += ws[w];
    if (t < nb) part[t] = x - v + add;   // exclusive
}

// scan3 + dinv + off sentinel fused
__global__ void k_scan3d(const int* __restrict__ in, const int* __restrict__ part,
                         int* __restrict__ off, float* __restrict__ dinv) {
    __shared__ int ws[4];
    int i = blockIdx.x * 256 + threadIdx.x;
    int lane = threadIdx.x & 63, wid = threadIdx.x >> 6;
    int v = (i < N_NODES) ? in[i] : 0;
    int x = wave_incl_scan(v, lane);
    if (lane == 63) ws[wid] = x;
    __syncthreads();
    int add = part[blockIdx.x];
    for (int w = 0; w < wid; ++w) add += ws[w];
    if (i < N_NODES) {
        off[i] = x - v + add;
        dinv[i] = 1.0f / sqrtf((float)(v + 1));   // +1 self loop
    }
    if (i == 0) off[N_NODES] = N_EDGES;
}

// ---------------- CSR fill (atomic-free) + xs = x*dinv scale, one kernel ----------------
__global__ void k_fill_scale(const int* __restrict__ row, const int* __restrict__ col,
                             const int* __restrict__ pos_e, const int* __restrict__ off,
                             int* __restrict__ csr_row,
                             const float4* __restrict__ x, const float* __restrict__ dinv,
                             float4* __restrict__ xs) {
    int idx = blockIdx.x * 256 + threadIdx.x;
    if (idx < N_EDGES) {
        int c = col[idx];
        int p = pos_e[idx];
        csr_row[off[c] + p] = row[idx];
    } else {
        int i = idx - N_EDGES;           // exactly N_NODES*16 of these
        int n = i >> 4;
        float d = dinv[n];
        float4 v = x[i];
        v.x *= d; v.y *= d; v.z *= d; v.w *= d;
        xs[i] = v;
    }
}

__device__ inline void f4add(float4& a, const float4 b) {
    a.x += b.x; a.y += b.y; a.z += b.z; a.w += b.w;
}

// ---------------- conv1 fused: gather xs (64ch) -> LDS -> vec-mat W1t -> h1s ----------------
// block: 256 threads, 16 nodes. Phase1: 16 lanes/node gather. Phase2: 8 col-groups x 2 nodes.
__global__ void k_conv1(const float4* __restrict__ xs, const int* __restrict__ csr_row,
                        const int* __restrict__ off, const float* __restrict__ dinv,
                        const float* __restrict__ w1t, const float* __restrict__ b1,
                        float* __restrict__ h1s) {
    __shared__ __align__(16) float agg[16][IN_CH + 4];
    int t = threadIdx.x;
    {   // phase 1: gather
        int local = t >> 4;           // 0..15
        int c4 = t & 15;              // float4 lane in 64ch
        int n = blockIdx.x * 16 + local;
        int s = off[n], e = off[n + 1];
        float4 acc = xs[n * 16 + c4];     // self term
        int i = s;
        for (; i + 8 <= e; i += 8) {
            int r0 = csr_row[i + 0], r1 = csr_row[i + 1], r2 = csr_row[i + 2], r3 = csr_row[i + 3];
            int r4 = csr_row[i + 4], r5 = csr_row[i + 5], r6 = csr_row[i + 6], r7 = csr_row[i + 7];
            float4 a0 = xs[r0 * 16 + c4], a1 = xs[r1 * 16 + c4];
            float4 a2 = xs[r2 * 16 + c4], a3 = xs[r3 * 16 + c4];
            float4 a4 = xs[r4 * 16 + c4], a5 = xs[r5 * 16 + c4];
            float4 a6 = xs[r6 * 16 + c4], a7 = xs[r7 * 16 + c4];
            f4add(a0, a1); f4add(a2, a3); f4add(a4, a5); f4add(a6, a7);
            f4add(a0, a2); f4add(a4, a6);
            f4add(a0, a4);
            f4add(acc, a0);
        }
        for (; i < e; ++i) {
            float4 a = xs[csr_row[i] * 16 + c4];
            f4add(acc, a);
        }
        float dn = dinv[n];
        acc.x *= dn; acc.y *= dn; acc.z *= dn; acc.w *= dn;
        *reinterpret_cast<float4*>(&agg[local][c4 * 4]) = acc;
    }
    __syncthreads();
    {   // phase 2: h1s[node][cq..cq+3] = relu(agg[node].W1t + b1)*dinv, 2 nodes/thread
        int cq = (t & 31) << 2;
        int rg = t >> 5;              // 0..7
        int na = rg * 2, nb = rg * 2 + 1;
        float4 bv = *reinterpret_cast<const float4*>(&b1[cq]);
        float4 acca = bv, accb = bv;
        #pragma unroll 4
        for (int k = 0; k < IN_CH; ++k) {
            float4 w = *reinterpret_cast<const float4*>(&w1t[k * EMB + cq]);
            float sa = agg[na][k], sb = agg[nb][k];
            acca.x = fmaf(sa, w.x, acca.x); acca.y = fmaf(sa, w.y, acca.y);
            acca.z = fmaf(sa, w.z, acca.z); acca.w = fmaf(sa, w.w, acca.w);
            accb.x = fmaf(sb, w.x, accb.x); accb.y = fmaf(sb, w.y, accb.y);
            accb.z = fmaf(sb, w.z, accb.z); accb.w = fmaf(sb, w.w, accb.w);
        }
        int base = blockIdx.x * 16;
        float da = dinv[base + na], db = dinv[base + nb];
        acca.x = fmaxf(acca.x, 0.f) * da; acca.y = fmaxf(acca.y, 0.f) * da;
        acca.z = fmaxf(acca.z, 0.f) * da; acca.w = fmaxf(acca.w, 0.f) * da;
        accb.x = fmaxf(accb.x, 0.f) * db; accb.y = fmaxf(accb.y, 0.f) * db;
        accb.z = fmaxf(accb.z, 0.f) * db; accb.w = fmaxf(accb.w, 0.f) * db;
        *reinterpret_cast<float4*>(&h1s[(size_t)(base + na) * EMB + cq]) = acca;
        *reinterpret_cast<float4*>(&h1s[(size_t)(base + nb) * EMB + cq]) = accb;
    }
}

// ---------------- conv2 fused: gather h1s (128ch) -> LDS -> vec-mat W2t -> relu -> readout ----------------
// block: 256 threads, 8 nodes. Phase1: 32 lanes/node gather. Phase2: 1 node x 4 cols/thread.
__global__ void k_conv2(const float4* __restrict__ h1s4, const int* __restrict__ csr_row,
                        const int* __restrict__ off, const float* __restrict__ dinv,
                        const float* __restrict__ w2t, const float* __restrict__ b2,
                        const int* __restrict__ batch, float* __restrict__ gsum) {
    __shared__ __align__(16) float agg[8][EMB + 4];
    __shared__ __align__(16) float hb[8][EMB + 4];
    __shared__ int bg[8];
    int t = threadIdx.x;
    int n0 = blockIdx.x * 8;
    if (t < 8) bg[t] = batch[n0 + t];
    {   // phase 1: gather (self term included; dinv applied post-GEMM)
        int local = t >> 5;           // 0..7
        int c4 = t & 31;
        int n = n0 + local;
        int s = off[n], e = off[n + 1];
        float4 acc = h1s4[(size_t)n * 32 + c4];
        int i = s;
        for (; i + 8 <= e; i += 8) {
            int r0 = csr_row[i + 0], r1 = csr_row[i + 1], r2 = csr_row[i + 2], r3 = csr_row[i + 3];
            int r4 = csr_row[i + 4], r5 = csr_row[i + 5], r6 = csr_row[i + 6], r7 = csr_row[i + 7];
            float4 a0 = h1s4[(size_t)r0 * 32 + c4], a1 = h1s4[(size_t)r1 * 32 + c4];
            float4 a2 = h1s4[(size_t)r2 * 32 + c4], a3 = h1s4[(size_t)r3 * 32 + c4];
            float4 a4 = h1s4[(size_t)r4 * 32 + c4], a5 = h1s4[(size_t)r5 * 32 + c4];
            float4 a6 = h1s4[(size_t)r6 * 32 + c4], a7 = h1s4[(size_t)r7 * 32 + c4];
            f4add(a0, a1); f4add(a2, a3); f4add(a4, a5); f4add(a6, a7);
            f4add(a0, a2); f4add(a4, a6);
            f4add(a0, a4);
            f4add(acc, a0);
        }
        for (; i < e; ++i) {
            float4 a = h1s4[(size_t)csr_row[i] * 32 + c4];
            f4add(acc, a);
        }
        *reinterpret_cast<float4*>(&agg[local][c4 * 4]) = acc;
    }
    __syncthreads();
    {   // phase 2: h2[node][cq..cq+3] = relu(dinv*agg.W2t + b2)
        int cq = (t & 31) << 2;
        int node = t >> 5;            // 0..7
        float4 acc = make_float4(0.f, 0.f, 0.f, 0.f);
        #pragma unroll 4
        for (int k = 0; k < EMB; ++k) {
            float4 w = *reinterpret_cast<const float4*>(&w2t[k * EMB + cq]);
            float s = agg[node][k];
            acc.x = fmaf(s, w.x, acc.x); acc.y = fmaf(s, w.y, acc.y);
            acc.z = fmaf(s, w.z, acc.z); acc.w = fmaf(s, w.w, acc.w);
        }
        float dn = dinv[n0 + node];
        float4 bv = *reinterpret_cast<const float4*>(&b2[cq]);
        acc.x = fmaxf(fmaf(acc.x, dn, bv.x), 0.f);
        acc.y = fmaxf(fmaf(acc.y, dn, bv.y), 0.f);
        acc.z = fmaxf(fmaf(acc.z, dn, bv.z), 0.f);
        acc.w = fmaxf(fmaf(acc.w, dn, bv.w), 0.f);
        *reinterpret_cast<float4*>(&hb[node][cq]) = acc;
    }
    __syncthreads();
    {   // phase 3: run-based readout (batch sorted)
        int ch = t;
        if (ch < EMB) {
            int g = bg[0];
            float a = 0.f;
            #pragma unroll
            for (int j = 0; j < 8; ++j) {
                int gj = bg[j];
                if (gj != g) { atomicAdd(&gsum[g * EMB + ch], a); a = 0.f; g = gj; }
                a += hb[j][ch];
            }
            atomicAdd(&gsum[g * EMB + ch], a);
        }
    }
}

// ---------------- digitize: presence + exclusive scan, one block ----------------
__global__ void k_digitize(const int* __restrict__ dd, int* __restrict__ rankx) {
    __shared__ int pres[N_GRAPHS];
    __shared__ int ws[4];
    __shared__ int carry;
    int t = threadIdx.x, lane = t & 63, wid = t >> 6;
    for (int i = t; i < N_GRAPHS; i += 256) pres[i] = 0;
    __syncthreads();
    for (int i = t; i < 2 * N_PAIRS; i += 256) pres[dd[i]] = 1;
    if (t == 0) carry = 0;
    __syncthreads();
    for (int base = 0; base < N_GRAPHS; base += 256) {
        int i = base + t;
        int v = (i < N_GRAPHS) ? pres[i] : 0;
        int x = wave_incl_scan(v, lane);
        if (lane == 63) ws[wid] = x;
        __syncthreads();
        int add = carry;
        for (int w = 0; w < wid; ++w) add += ws[w];
        if (i < N_GRAPHS) rankx[i] = x - v + add;
        __syncthreads();
        if (t == 255) carry = add + x;
        __syncthreads();
    }
}

// ---------------- pair MLP, 16 pairs/block, mean-division fused at load ----------------
__global__ void k_mlp16(const float* __restrict__ gemb, const int* __restrict__ cnt,
                        const int* __restrict__ dd, const int* __restrict__ rankx,
                        const float* __restrict__ w1, const float* __restrict__ b1,
                        const float* __restrict__ w2, const float* __restrict__ b2,
                        float* __restrict__ out) {
    __shared__ __align__(16) float pv[PPB][2 * EMB];
    __shared__ float wpart[4][PPB];
    int p0 = blockIdx.x * PPB;
    int t = threadIdx.x;             // 0..255
    int lane = t & 63, wid = t >> 6;
    #pragma unroll
    for (int j = 0; j < PPB; ++j) {
        int p = p0 + j;
        if (t < EMB) {
            int ga = rankx[dd[p]];
            int ca = cnt[ga];
            float ra = 1.0f / (float)(ca > 1 ? ca : 1);
            pv[j][t] = gemb[ga * EMB + t] * ra;
        } else {
            int gb = rankx[dd[N_PAIRS + p]];
            int cb = cnt[gb];
            float rb = 1.0f / (float)(cb > 1 ? cb : 1);
            pv[j][t] = gemb[gb * EMB + (t - EMB)] * rb;
        }
    }
    __syncthreads();
    float acc[PPB];
    float bv = b1[t];
    #pragma unroll
    for (int j = 0; j < PPB; ++j) acc[j] = bv;
    const float4* wrow = reinterpret_cast<const float4*>(&w1[t * 2 * EMB]);
    for (int k = 0; k < (2 * EMB) / 4; ++k) {
        float4 w = wrow[k];
        #pragma unroll
        for (int j = 0; j < PPB; ++j) {
            const float4 xv = *reinterpret_cast<const float4*>(&pv[j][k * 4]);
            acc[j] = fmaf(xv.x, w.x, fmaf(xv.y, w.y, fmaf(xv.z, w.z, fmaf(xv.w, w.w, acc[j]))));
        }
    }
    float w2t = w2[t];
    float contrib[PPB];
    #pragma unroll
    for (int j = 0; j < PPB; ++j) contrib[j] = fmaxf(acc[j], 0.f) * w2t;
    #pragma unroll
    for (int off = 32; off > 0; off >>= 1) {
        #pragma unroll
        for (int j = 0; j < PPB; ++j) contrib[j] += __shfl_down(contrib[j], off, 64);
    }
    if (lane == 0) {
        #pragma unroll
        for (int j = 0; j < PPB; ++j) wpart[wid][j] = contrib[j];
    }
    __syncthreads();
    if (t < PPB) {
        out[p0 + t] = wpart[0][t] + wpart[1][t] + wpart[2][t] + wpart[3][t] + b2[0];
    }
}

extern "C" void kernel_launch(void* const* d_in, const int* in_sizes, int n_in,
                              void* d_out, int out_size, void* d_ws, size_t ws_size,
                              hipStream_t stream) {
    const float* x        = (const float*)d_in[0];
    const int*   ei       = (const int*)d_in[1];      // [2, E]
    const int*   batch    = (const int*)d_in[2];
    const int*   dd       = (const int*)d_in[3];      // [2, P]
    const float* conv1_w  = (const float*)d_in[4];
    const float* conv1_b  = (const float*)d_in[5];
    const float* conv2_w  = (const float*)d_in[6];
    const float* conv2_b  = (const float*)d_in[7];
    const float* reg1_w   = (const float*)d_in[8];
    const float* reg1_b   = (const float*)d_in[9];
    const float* reg2_w   = (const float*)d_in[10];
    const float* reg2_b   = (const float*)d_in[11];
    float* outp = (float*)d_out;

    const int* ei_row = ei;
    const int* ei_col = ei + N_EDGES;

    // ---- workspace layout ----
    char* ws = (char*)d_ws;
    size_t o = 0;
    auto alloc = [&](size_t bytes) -> void* {
        void* p = ws + o;
        o = (o + bytes + 255) & ~(size_t)255;
        return p;
    };
    size_t zero_start = o;
    int*   deg     = (int*)alloc(N_NODES * 4);
    int*   cnt     = (int*)alloc(N_GRAPHS * 4);
    float* gsum    = (float*)alloc(N_GRAPHS * EMB * 4);
    size_t zero_bytes = o - zero_start;
    int*   off     = (int*)alloc((N_NODES + 1) * 4);
    float* dinv    = (float*)alloc(N_NODES * 4);
    int*   part    = (int*)alloc(256 * 4);
    int*   pos_e   = (int*)alloc(N_EDGES * 4);
    int*   csr_row = (int*)alloc(N_EDGES * 4);
    int*   rankx   = (int*)alloc(N_GRAPHS * 4);
    float* Wt1     = (float*)alloc(IN_CH * EMB * 4);
    float* Wt2     = (float*)alloc(EMB * EMB * 4);
    float* xs      = (float*)alloc((size_t)N_NODES * IN_CH * 4);
    float* h1s     = (float*)alloc((size_t)N_NODES * EMB * 4);

    (void)ws_size; (void)in_sizes; (void)n_in; (void)out_size;

    hipMemsetAsync(ws + zero_start, 0, zero_bytes, stream);

    // pre: deg + per-edge rank + graph counts + weight transposes
    k_pre<<<N_EDGES / 256, 256, 0, stream>>>(ei_col, batch, conv1_w, conv2_w,
                                             deg, pos_e, cnt, Wt1, Wt2);
    {
        int nb = (N_NODES + 255) / 256;   // 196
        k_scan1<<<nb, 256, 0, stream>>>(deg, part, N_NODES);
        k_scan2<<<1, 256, 0, stream>>>(part, nb);
        k_scan3d<<<nb, 256, 0, stream>>>(deg, part, off, dinv);
    }
    k_fill_scale<<<(N_EDGES + N_NODES * (IN_CH / 4)) / 256, 256, 0, stream>>>(
        ei_row, ei_col, pos_e, off, csr_row, (const float4*)x, dinv, (float4*)xs);

    // conv1 fused: gather(64ch) + GEMM1 + bias + relu + dinv postscale
    k_conv1<<<N_NODES / 16, 256, 0, stream>>>(
        (const float4*)xs, csr_row, off, dinv, Wt1, conv1_b, h1s);

    // conv2 fused: gather(128ch) + GEMM2 + bias + relu + readout
    k_conv2<<<N_NODES / 8, 256, 0, stream>>>(
        (const float4*)h1s, csr_row, off, dinv, Wt2, conv2_b, batch, gsum);

    // digitize-rank (one block)
    k_digitize<<<1, 256, 0, stream>>>(dd, rankx);

    // pair MLP (mean division fused)
    k_mlp16<<<N_PAIRS / PPB, 256, 0, stream>>>(gsum, cnt, dd, rankx,
                                               reg1_w, reg1_b, reg2_w, reg2_b, outp);
}